// Round 1
// baseline (112.760 us; speedup 1.0000x reference)
//
#include <hip/hip_runtime.h>
#include <hip/hip_bf16.h>

#define NUM_LAYERS 16
#define BATCH 64
#define SEQ 128
#define DIM 1024
#define OUTD 1024

typedef __bf16 bf16x8 __attribute__((ext_vector_type(8)));
typedef float f32x4 __attribute__((ext_vector_type(4)));

// round-to-nearest-even f32 -> bf16, two at a time packed into u32
__device__ __forceinline__ unsigned f2bf2(float a, float b) {
    union { float f; unsigned u; } x{a}, y{b};
    unsigned lo = x.u + 0x7FFFu + ((x.u >> 16) & 1u);
    unsigned hi = y.u + 0x7FFFu + ((y.u >> 16) & 1u);
    return (lo >> 16) | (hi & 0xFFFF0000u);
}

// Block tile: M=64 (all of batch), N=128, K-step 64. 4 waves, each wave owns
// a 64x32 output sub-tile = 4x2 fragments of 16x16, mfma_f32_16x16x32_bf16.
// LDS tiles bf16 with XOR swizzle (byte ^= (row&7)<<4) so the 128B row stride
// doesn't produce a 32-way bank conflict on ds_read_b128 (guide G4).
__global__ __launch_bounds__(256) void moshi_flin_mfma(
    const float* __restrict__ x, const int* __restrict__ lidx,
    const float* __restrict__ w, float* __restrict__ out) {
    __shared__ __align__(16) unsigned char lx[64 * 128];    // 64 rows x 64 bf16 = 8 KB
    __shared__ __align__(16) unsigned char lw[128 * 128];   // 128 rows x 64 bf16 = 16 KB

    const int bid = blockIdx.x;
    const int s   = bid >> 3;          // 0..127
    const int n0  = (bid & 7) << 7;    // 0,128,...,896
    const int tid = threadIdx.x;
    const int lane = tid & 63;
    const int wid  = tid >> 6;

    const int idx = lidx[s];
    const float* wb = w + (size_t)idx * OUTD * DIM + (size_t)n0 * DIM;
    const float* xb = x + (size_t)s * DIM;   // + b*SEQ*DIM per row

    // fragment read addressing (per-lane constants)
    const int swz    = (lane & 7) << 4;          // XOR swizzle bits 4-6
    const int kb     = (lane >> 4) << 4;         // byte offset of 8-elem k-group
    const int a_base = (lane & 15) * 128 + kb;
    const int b_base = (wid * 32 + (lane & 15)) * 128 + kb;

    f32x4 acc[4][2];
    #pragma unroll
    for (int i = 0; i < 4; ++i)
        #pragma unroll
        for (int j = 0; j < 2; ++j)
            acc[i][j] = (f32x4)0.0f;

    for (int kt = 0; kt < DIM; kt += 64) {
        __syncthreads();   // previous compute done before overwrite
        // stage x tile: 64 rows(b) x 64 cols(k) fp32 -> bf16. 1024 float4, 4 passes.
        #pragma unroll
        for (int p = 0; p < 4; ++p) {
            int f = tid + p * 256;
            int row = f >> 4;              // batch row
            int c   = (f & 15) << 2;       // float col within BK
            const float4 v = *reinterpret_cast<const float4*>(
                xb + (size_t)row * (SEQ * DIM) + kt + c);
            uint2 pk = { f2bf2(v.x, v.y), f2bf2(v.z, v.w) };
            int bo = (row * 128 + c * 2) ^ ((row & 7) << 4);
            *reinterpret_cast<uint2*>(&lx[bo]) = pk;
        }
        // stage w tile: 128 rows(o) x 64 cols(k). 2048 float4, 8 passes.
        #pragma unroll
        for (int p = 0; p < 8; ++p) {
            int f = tid + p * 256;
            int row = f >> 4;
            int c   = (f & 15) << 2;
            const float4 v = *reinterpret_cast<const float4*>(
                wb + (size_t)row * DIM + kt + c);
            uint2 pk = { f2bf2(v.x, v.y), f2bf2(v.z, v.w) };
            int bo = (row * 128 + c * 2) ^ ((row & 7) << 4);
            *reinterpret_cast<uint2*>(&lw[bo]) = pk;
        }
        __syncthreads();

        #pragma unroll
        for (int kk = 0; kk < 2; ++kk) {
            bf16x8 af[4], bfr[2];
            #pragma unroll
            for (int mi = 0; mi < 4; ++mi)
                af[mi] = *reinterpret_cast<const bf16x8*>(
                    &lx[(((a_base + kk * 64) ^ swz) + mi * 2048)]);
            #pragma unroll
            for (int ni = 0; ni < 2; ++ni)
                bfr[ni] = *reinterpret_cast<const bf16x8*>(
                    &lw[(((b_base + kk * 64) ^ swz) + ni * 2048)]);
            #pragma unroll
            for (int mi = 0; mi < 4; ++mi)
                #pragma unroll
                for (int ni = 0; ni < 2; ++ni)
                    acc[mi][ni] = __builtin_amdgcn_mfma_f32_16x16x32_bf16(
                        af[mi], bfr[ni], acc[mi][ni], 0, 0, 0);
        }
    }

    // epilogue: C/D layout col = lane&15 (o), row = (lane>>4)*4 + reg (b)
    float* ob = out + (size_t)s * OUTD + n0 + wid * 32 + (lane & 15);
    const int r0 = (lane >> 4) << 2;
    #pragma unroll
    for (int mi = 0; mi < 4; ++mi)
        #pragma unroll
        for (int ni = 0; ni < 2; ++ni)
            #pragma unroll
            for (int r = 0; r < 4; ++r) {
                int b = mi * 16 + r0 + r;
                ob[(size_t)b * (SEQ * OUTD) + ni * 16] = acc[mi][ni][r];
            }
}

extern "C" void kernel_launch(void* const* d_in, const int* in_sizes, int n_in,
                              void* d_out, int out_size, void* d_ws, size_t ws_size,
                              hipStream_t stream) {
    const float* x   = (const float*)d_in[0];
    const int* lidx  = (const int*)d_in[1];
    const float* w   = (const float*)d_in[2];
    float* out       = (float*)d_out;
    // grid: 128 s-positions x 8 N-tiles
    moshi_flin_mfma<<<dim3(128 * 8), dim3(256), 0, stream>>>(x, lidx, w, out);
}

// Round 2
// 78.090 us; speedup vs baseline: 1.4440x; 1.4440x over previous
//
#include <hip/hip_runtime.h>
#include <hip/hip_bf16.h>

#define B_ 64
#define S_ 128
#define D_ 1024
#define O_ 1024
#define L_ 16

typedef __bf16 bf16x8 __attribute__((ext_vector_type(8)));
typedef float f32x4 __attribute__((ext_vector_type(4)));

// ws layout (bytes):
//  [0, 33554432)        W bf16, tiles [l][nt:8][kt:16], each 128(o-rows) x 64(k) bf16 = 16384 B, XOR-swizzled
//  [33554432, 50331648) x bf16, tiles [s:128][kt:16], each 64(b-rows) x 64(k) bf16 = 8192 B, XOR-swizzled
//  [50331648]           npairs (int, 16-byte slot)
//  [50331664, +72*16)   pairs int4 {s0, s1, layer, 0}
#define WS_W   0ull
#define WS_X   33554432ull
#define WS_P   50331648ull
#define WS_NEED (50331664ull + 72ull * 16ull)

// round-to-nearest-even f32 -> bf16, two packed into u32
__device__ __forceinline__ unsigned f2bf2(float a, float b) {
    union { float f; unsigned u; } x{a}, y{b};
    unsigned lo = x.u + 0x7FFFu + ((x.u >> 16) & 1u);
    unsigned hi = y.u + 0x7FFFu + ((y.u >> 16) & 1u);
    return (lo >> 16) | (hi & 0xFFFF0000u);
}

__device__ __forceinline__ void gload16(const void* g, void* l) {
    __builtin_amdgcn_global_load_lds(
        (const __attribute__((address_space(1))) void*)g,
        (__attribute__((address_space(3))) void*)l, 16, 0, 0);
}

// ---- pass 0: group s-positions by layer into pairs (padded with duplicate) ----
__global__ void moshi_build_pairs(const int* __restrict__ lidx, int* __restrict__ pws) {
    __shared__ int cnt[16];
    int t = threadIdx.x;
    if (t < 16) {
        int c = 0;
        for (int s = 0; s < S_; ++s) c += (lidx[s] == t);
        cnt[t] = c;
    }
    __syncthreads();
    if (t < 16) {
        int off = 0;
        for (int m = 0; m < t; ++m) off += (cnt[m] + 1) >> 1;
        int4* pairs = (int4*)((char*)pws + 16);
        int k = 0, prev = -1;
        for (int s = 0; s < S_; ++s) {
            if (lidx[s] == t) {
                if (k & 1) pairs[off + (k >> 1)] = make_int4(prev, s, t, 0);
                prev = s; ++k;
            }
        }
        if (k & 1) pairs[off + (k >> 1)] = make_int4(prev, prev, t, 0);
        if (t == 0) {
            int tot = 0;
            for (int m = 0; m < 16; ++m) tot += (cnt[m] + 1) >> 1;
            pws[0] = tot;
        }
    }
}

// ---- pass 1: fp32 -> bf16 conversion into pre-swizzled tiles ----
__global__ __launch_bounds__(256) void moshi_convert(
    const float* __restrict__ x, const float* __restrict__ w,
    unsigned char* __restrict__ ws) {
    const int TW = L_ * O_ * D_ / 4;   // 4194304 float4 groups
    const int TX = B_ * S_ * D_ / 4;   // 2097152
    for (int f = blockIdx.x * 256 + threadIdx.x; f < TW + TX; f += gridDim.x * 256) {
        if (f < TW) {
            const float4 v = *reinterpret_cast<const float4*>(w + 4ull * f);
            uint2 pk = { f2bf2(v.x, v.y), f2bf2(v.z, v.w) };
            int d4 = f & 255, o = (f >> 8) & 1023, l = f >> 18;
            int nt = o >> 7, row = o & 127, kt = d4 >> 4;
            unsigned byte = ((unsigned)((l * 8 + nt) * 16 + kt)) * 16384u
                          + (((unsigned)(row * 128 + (d4 & 15) * 8)) ^ ((row & 7) << 4));
            *reinterpret_cast<uint2*>(ws + WS_W + byte) = pk;
        } else {
            int g = f - TW;
            const float4 v = *reinterpret_cast<const float4*>(x + 4ull * g);
            uint2 pk = { f2bf2(v.x, v.y), f2bf2(v.z, v.w) };
            int d4 = g & 255, s = (g >> 8) & 127, b = g >> 15;
            int kt = d4 >> 4;
            unsigned byte = ((unsigned)(s * 16 + kt)) * 8192u
                          + (((unsigned)(b * 128 + (d4 & 15) * 8)) ^ ((b & 7) << 4));
            *reinterpret_cast<uint2*>(ws + WS_X + byte) = pk;
        }
    }
}

// ---- pass 2: paired GEMM. Block = (pair, nt). Tile M=128 (2s x 64b), N=128, BK=64.
// 4 waves (2x2), each owns 64x64 = 4x4 fragments. m97-style 2-barrier loop,
// global_load_lds width 16 from pre-swizzled ws tiles.
__global__ __launch_bounds__(256) void moshi_gemm_paired(
    const unsigned char* __restrict__ ws, float* __restrict__ out) {
    __shared__ __align__(16) unsigned char lw[16384];   // 128 x 64 bf16 (swizzled)
    __shared__ __align__(16) unsigned char lx[16384];   // 2 x (64 x 64) bf16 (swizzled)

    const int np = *reinterpret_cast<const int*>(ws + WS_P);
    const int pi = blockIdx.x >> 3;
    const int nt = blockIdx.x & 7;
    if (pi >= np) return;
    const int4 pr = *reinterpret_cast<const int4*>(ws + WS_P + 16 + 16ull * pi);
    const int s0 = pr.x, s1 = pr.y, l = pr.z;

    const unsigned char* wt  = ws + WS_W + ((size_t)(l * 8 + nt) * 16) * 16384;
    const unsigned char* xt0 = ws + WS_X + (size_t)s0 * 16 * 8192;
    const unsigned char* xt1 = ws + WS_X + (size_t)s1 * 16 * 8192;

    const int tid = threadIdx.x, lane = tid & 63, wid = tid >> 6;
    const int wm = wid >> 1, wn = wid & 1;
    const int swz = (lane & 7) << 4;
    const int kb  = (lane >> 4) << 4;
    const int a_base = (wm * 64 + (lane & 15)) * 128 + kb;
    const int b_base = (wn * 64 + (lane & 15)) * 128 + kb;

    f32x4 acc[4][4];
    #pragma unroll
    for (int i = 0; i < 4; ++i)
        #pragma unroll
        for (int j = 0; j < 4; ++j)
            acc[i][j] = (f32x4)0.0f;

    for (int kt = 0; kt < 16; ++kt) {
        __syncthreads();   // previous compute done before overwrite
        #pragma unroll
        for (int p = 0; p < 4; ++p)
            gload16(wt + (size_t)kt * 16384 + tid * 16 + p * 4096,
                    lw + tid * 16 + p * 4096);
        gload16(xt0 + (size_t)kt * 8192 + tid * 16,        lx + tid * 16);
        gload16(xt0 + (size_t)kt * 8192 + tid * 16 + 4096, lx + tid * 16 + 4096);
        gload16(xt1 + (size_t)kt * 8192 + tid * 16,        lx + 8192 + tid * 16);
        gload16(xt1 + (size_t)kt * 8192 + tid * 16 + 4096, lx + 8192 + tid * 16 + 4096);
        __syncthreads();   // stage complete (compiler drains vmcnt before barrier)

        #pragma unroll
        for (int kk = 0; kk < 2; ++kk) {
            bf16x8 af[4], bf[4];
            #pragma unroll
            for (int mi = 0; mi < 4; ++mi)
                af[mi] = *reinterpret_cast<const bf16x8*>(
                    lx + (((a_base + kk * 64) ^ swz) + mi * 2048));
            #pragma unroll
            for (int ni = 0; ni < 4; ++ni)
                bf[ni] = *reinterpret_cast<const bf16x8*>(
                    lw + (((b_base + kk * 64) ^ swz) + ni * 2048));
            #pragma unroll
            for (int mi = 0; mi < 4; ++mi)
                #pragma unroll
                for (int ni = 0; ni < 4; ++ni)
                    acc[mi][ni] = __builtin_amdgcn_mfma_f32_16x16x32_bf16(
                        af[mi], bf[ni], acc[mi][ni], 0, 0, 0);
        }
    }

    // epilogue: C/D col = lane&15 (o), row = (lane>>4)*4 + reg (b)
    const int s_sel = wm ? s1 : s0;
    const int col0 = nt * 128 + wn * 64 + (lane & 15);
    const int r0 = (lane >> 4) << 2;
    #pragma unroll
    for (int mi = 0; mi < 4; ++mi)
        #pragma unroll
        for (int ni = 0; ni < 4; ++ni)
            #pragma unroll
            for (int r = 0; r < 4; ++r) {
                int b = mi * 16 + r0 + r;
                out[((size_t)b * S_ + s_sel) * O_ + col0 + ni * 16] = acc[mi][ni][r];
            }
}

// ---- fallback (round-1 kernel) if ws is too small ----
__global__ __launch_bounds__(256) void moshi_flin_fallback(
    const float* __restrict__ x, const int* __restrict__ lidx,
    const float* __restrict__ w, float* __restrict__ out) {
    __shared__ __align__(16) unsigned char lxs[64 * 128];
    __shared__ __align__(16) unsigned char lws[128 * 128];
    const int bid = blockIdx.x;
    const int s = bid >> 3, n0 = (bid & 7) << 7;
    const int tid = threadIdx.x, lane = tid & 63, wid = tid >> 6;
    const int idx = lidx[s];
    const float* wb = w + (size_t)idx * O_ * D_ + (size_t)n0 * D_;
    const float* xb = x + (size_t)s * D_;
    const int swz = (lane & 7) << 4;
    const int kb = (lane >> 4) << 4;
    const int a_base = (lane & 15) * 128 + kb;
    const int b_base = (wid * 32 + (lane & 15)) * 128 + kb;
    f32x4 acc[4][2];
    #pragma unroll
    for (int i = 0; i < 4; ++i)
        #pragma unroll
        for (int j = 0; j < 2; ++j) acc[i][j] = (f32x4)0.0f;
    for (int kt = 0; kt < D_; kt += 64) {
        __syncthreads();
        #pragma unroll
        for (int p = 0; p < 4; ++p) {
            int f = tid + p * 256, row = f >> 4, c = (f & 15) << 2;
            const float4 v = *reinterpret_cast<const float4*>(
                xb + (size_t)row * (S_ * D_) + kt + c);
            uint2 pk = { f2bf2(v.x, v.y), f2bf2(v.z, v.w) };
            *reinterpret_cast<uint2*>(&lxs[(row * 128 + c * 2) ^ ((row & 7) << 4)]) = pk;
        }
        #pragma unroll
        for (int p = 0; p < 8; ++p) {
            int f = tid + p * 256, row = f >> 4, c = (f & 15) << 2;
            const float4 v = *reinterpret_cast<const float4*>(
                wb + (size_t)row * D_ + kt + c);
            uint2 pk = { f2bf2(v.x, v.y), f2bf2(v.z, v.w) };
            *reinterpret_cast<uint2*>(&lws[(row * 128 + c * 2) ^ ((row & 7) << 4)]) = pk;
        }
        __syncthreads();
        #pragma unroll
        for (int kk = 0; kk < 2; ++kk) {
            bf16x8 af[4], bfr[2];
            #pragma unroll
            for (int mi = 0; mi < 4; ++mi)
                af[mi] = *reinterpret_cast<const bf16x8*>(
                    &lxs[(((a_base + kk * 64) ^ swz) + mi * 2048)]);
            #pragma unroll
            for (int ni = 0; ni < 2; ++ni)
                bfr[ni] = *reinterpret_cast<const bf16x8*>(
                    &lws[(((b_base + kk * 64) ^ swz) + ni * 2048)]);
            #pragma unroll
            for (int mi = 0; mi < 4; ++mi)
                #pragma unroll
                for (int ni = 0; ni < 2; ++ni)
                    acc[mi][ni] = __builtin_amdgcn_mfma_f32_16x16x32_bf16(
                        af[mi], bfr[ni], acc[mi][ni], 0, 0, 0);
        }
    }
    float* ob = out + (size_t)s * O_ + n0 + wid * 32 + (lane & 15);
    const int r0 = (lane >> 4) << 2;
    #pragma unroll
    for (int mi = 0; mi < 4; ++mi)
        #pragma unroll
        for (int ni = 0; ni < 2; ++ni)
            #pragma unroll
            for (int r = 0; r < 4; ++r) {
                int b = mi * 16 + r0 + r;
                ob[(size_t)b * (S_ * O_) + ni * 16] = acc[mi][ni][r];
            }
}

extern "C" void kernel_launch(void* const* d_in, const int* in_sizes, int n_in,
                              void* d_out, int out_size, void* d_ws, size_t ws_size,
                              hipStream_t stream) {
    const float* x  = (const float*)d_in[0];
    const int* lidx = (const int*)d_in[1];
    const float* w  = (const float*)d_in[2];
    float* out      = (float*)d_out;

    if (ws_size < WS_NEED) {
        moshi_flin_fallback<<<dim3(128 * 8), dim3(256), 0, stream>>>(x, lidx, w, out);
        return;
    }
    unsigned char* ws = (unsigned char*)d_ws;
    moshi_build_pairs<<<dim3(1), dim3(64), 0, stream>>>(lidx, (int*)(ws + WS_P));
    moshi_convert<<<dim3(4096), dim3(256), 0, stream>>>(x, w, ws);
    // grid: 72 pair slots x 8 n-tiles (blocks beyond npairs exit early)
    moshi_gemm_paired<<<dim3(72 * 8), dim3(256), 0, stream>>>(ws, out);
}

// Round 3
// 66.061 us; speedup vs baseline: 1.7069x; 1.1821x over previous
//
#include <hip/hip_runtime.h>
#include <hip/hip_bf16.h>

#define B_ 64
#define S_ 128
#define D_ 1024
#define O_ 1024
#define L_ 16

typedef __bf16 bf16x8 __attribute__((ext_vector_type(8)));
typedef float f32x4 __attribute__((ext_vector_type(4)));

// ws layout (bytes):
//  [0, 33554432)        W bf16, tiles [l][nt:8][kt:16], each 128(o) x 64(k) bf16 = 16384 B, XOR-swizzled
//  [33554432, 50331648) x bf16, tiles [s:128][kt:16], each 64(b) x 64(k) bf16 = 8192 B, XOR-swizzled
//  [50331648]           npairs (int, 16-byte slot)
//  [50331664, +72*16)   pairs int4 {s0, s1, layer, 0}
#define WS_W   0ull
#define WS_X   33554432ull
#define WS_P   50331648ull
#define WS_NEED (50331664ull + 72ull * 16ull)

// round-to-nearest-even f32 -> bf16, two packed into u32
__device__ __forceinline__ unsigned f2bf2(float a, float b) {
    union { float f; unsigned u; } x{a}, y{b};
    unsigned lo = x.u + 0x7FFFu + ((x.u >> 16) & 1u);
    unsigned hi = y.u + 0x7FFFu + ((y.u >> 16) & 1u);
    return (lo >> 16) | (hi & 0xFFFF0000u);
}

__device__ __forceinline__ void gload16(const void* g, void* l) {
    __builtin_amdgcn_global_load_lds(
        (const __attribute__((address_space(1))) void*)g,
        (__attribute__((address_space(3))) void*)l, 16, 0, 0);
}

// ---- pass 1: fp32 -> bf16 conversion into pre-swizzled tiles.
// Block 0 lanes 0-15 additionally build the layer-grouped s-pairs (independent of converts).
__global__ __launch_bounds__(256) void moshi_convert(
    const float* __restrict__ x, const float* __restrict__ w,
    const int* __restrict__ lidx, unsigned char* __restrict__ ws) {
    if (blockIdx.x == 0 && threadIdx.x < 16) {
        int t = threadIdx.x;
        // per-layer counts (each lane scans lidx; S=128 so cheap, L2-resident)
        int cnt[16];
        #pragma unroll 1
        for (int m = 0; m < 16; ++m) cnt[m] = 0;
        for (int s = 0; s < S_; ++s) ++cnt[lidx[s]];
        int off = 0;
        for (int m = 0; m < t; ++m) off += (cnt[m] + 1) >> 1;
        int4* pairs = (int4*)(ws + WS_P + 16);
        int k = 0, prev = -1;
        for (int s = 0; s < S_; ++s) {
            if (lidx[s] == t) {
                if (k & 1) pairs[off + (k >> 1)] = make_int4(prev, s, t, 0);
                prev = s; ++k;
            }
        }
        if (k & 1) pairs[off + (k >> 1)] = make_int4(prev, prev, t, 0);
        if (t == 0) {
            int tot = 0;
            for (int m = 0; m < 16; ++m) tot += (cnt[m] + 1) >> 1;
            *(int*)(ws + WS_P) = tot;
        }
    }
    const int TW = L_ * O_ * D_ / 4;   // 4194304 float4 groups
    const int TX = B_ * S_ * D_ / 4;   // 2097152
    for (int f = blockIdx.x * 256 + threadIdx.x; f < TW + TX; f += gridDim.x * 256) {
        if (f < TW) {
            const float4 v = *reinterpret_cast<const float4*>(w + 4ull * f);
            uint2 pk = { f2bf2(v.x, v.y), f2bf2(v.z, v.w) };
            int d4 = f & 255, o = (f >> 8) & 1023, l = f >> 18;
            int nt = o >> 7, row = o & 127, kt = d4 >> 4;
            unsigned byte = ((unsigned)((l * 8 + nt) * 16 + kt)) * 16384u
                          + (((unsigned)(row * 128 + (d4 & 15) * 8)) ^ ((row & 7) << 4));
            *reinterpret_cast<uint2*>(ws + WS_W + byte) = pk;
        } else {
            int g = f - TW;
            const float4 v = *reinterpret_cast<const float4*>(x + 4ull * g);
            uint2 pk = { f2bf2(v.x, v.y), f2bf2(v.z, v.w) };
            int d4 = g & 255, s = (g >> 8) & 127, b = g >> 15;
            int kt = d4 >> 4;
            unsigned byte = ((unsigned)(s * 16 + kt)) * 8192u
                          + (((unsigned)(b * 128 + (d4 & 15) * 8)) ^ ((b & 7) << 4));
            *reinterpret_cast<uint2*>(ws + WS_X + byte) = pk;
        }
    }
}

// ---- pass 2: paired GEMM, M=128 (2s x 64b), N=128, BK=64, 4 waves (2x2),
// each wave 64x64 = 4x4 fragments. Double-buffered LDS, single barrier per
// K-step, stage issued BEFORE compute so the compiler's vmcnt(0) drain at the
// barrier lands after the MFMAs (T3-minimum 2-phase). XCD-chunked bid swizzle.
__global__ __launch_bounds__(256) void moshi_gemm_paired(
    const unsigned char* __restrict__ ws, float* __restrict__ out) {
    __shared__ __align__(16) unsigned char lw[2][16384];   // 128 x 64 bf16 (swizzled)
    __shared__ __align__(16) unsigned char lx[2][16384];   // 2 x (64 x 64) bf16 (swizzled)

    // bijective XCD-chunk swizzle: grid 576 = 8 XCD chunks of 72 (9 pairs x 8 nt)
    const int bid = (blockIdx.x & 7) * 72 + (blockIdx.x >> 3);
    const int pi = bid >> 3;
    const int nt = bid & 7;
    const int np = *reinterpret_cast<const int*>(ws + WS_P);
    if (pi >= np) return;
    const int4 pr = *reinterpret_cast<const int4*>(ws + WS_P + 16 + 16ull * pi);
    const int s0 = pr.x, s1 = pr.y, l = pr.z;

    const unsigned char* wt  = ws + WS_W + ((size_t)(l * 8 + nt) * 16) * 16384;
    const unsigned char* xt0 = ws + WS_X + (size_t)s0 * 16 * 8192;
    const unsigned char* xt1 = ws + WS_X + (size_t)s1 * 16 * 8192;

    const int tid = threadIdx.x, lane = tid & 63, wid = tid >> 6;
    const int wm = wid >> 1, wn = wid & 1;
    const int swz = (lane & 7) << 4;
    const int kb  = (lane >> 4) << 4;
    const int a_base = (wm * 64 + (lane & 15)) * 128 + kb;
    const int b_base = (wn * 64 + (lane & 15)) * 128 + kb;

    f32x4 acc[4][4];
    #pragma unroll
    for (int i = 0; i < 4; ++i)
        #pragma unroll
        for (int j = 0; j < 4; ++j)
            acc[i][j] = (f32x4)0.0f;

    auto STAGE = [&](int kt, int b) {
        #pragma unroll
        for (int p = 0; p < 4; ++p)
            gload16(wt + (size_t)kt * 16384 + tid * 16 + p * 4096,
                    &lw[b][tid * 16 + p * 4096]);
        gload16(xt0 + (size_t)kt * 8192 + tid * 16,        &lx[b][tid * 16]);
        gload16(xt0 + (size_t)kt * 8192 + tid * 16 + 4096, &lx[b][tid * 16 + 4096]);
        gload16(xt1 + (size_t)kt * 8192 + tid * 16,        &lx[b][8192 + tid * 16]);
        gload16(xt1 + (size_t)kt * 8192 + tid * 16 + 4096, &lx[b][8192 + tid * 16 + 4096]);
    };

    STAGE(0, 0);
    __syncthreads();                      // buf0 ready (one full-latency drain)

    #pragma unroll 1
    for (int kt = 0; kt < 16; ++kt) {
        const int cur = kt & 1;
        if (kt < 15) STAGE(kt + 1, cur ^ 1);   // prefetch next tile first
        const unsigned char* lxb = lx[cur];
        const unsigned char* lwb = lw[cur];
        #pragma unroll
        for (int kk = 0; kk < 2; ++kk) {
            bf16x8 af[4], bf[4];
            #pragma unroll
            for (int mi = 0; mi < 4; ++mi)
                af[mi] = *reinterpret_cast<const bf16x8*>(
                    lxb + (((a_base + kk * 64) ^ swz) + mi * 2048));
            #pragma unroll
            for (int ni = 0; ni < 4; ++ni)
                bf[ni] = *reinterpret_cast<const bf16x8*>(
                    lwb + (((b_base + kk * 64) ^ swz) + ni * 2048));
            #pragma unroll
            for (int mi = 0; mi < 4; ++mi)
                #pragma unroll
                for (int ni = 0; ni < 4; ++ni)
                    acc[mi][ni] = __builtin_amdgcn_mfma_f32_16x16x32_bf16(
                        af[mi], bf[ni], acc[mi][ni], 0, 0, 0);
        }
        __syncthreads();   // drains vmcnt(0) AFTER compute; protects buf swap
    }

    // epilogue: C/D col = lane&15 (o), row = (lane>>4)*4 + reg (b)
    const int s_sel = wm ? s1 : s0;
    const int col0 = nt * 128 + wn * 64 + (lane & 15);
    const int r0 = (lane >> 4) << 2;
    #pragma unroll
    for (int mi = 0; mi < 4; ++mi)
        #pragma unroll
        for (int ni = 0; ni < 4; ++ni)
            #pragma unroll
            for (int r = 0; r < 4; ++r) {
                int b = mi * 16 + r0 + r;
                out[((size_t)b * S_ + s_sel) * O_ + col0 + ni * 16] = acc[mi][ni][r];
            }
}

// ---- fallback (round-1 kernel) if ws is too small ----
__global__ __launch_bounds__(256) void moshi_flin_fallback(
    const float* __restrict__ x, const int* __restrict__ lidx,
    const float* __restrict__ w, float* __restrict__ out) {
    __shared__ __align__(16) unsigned char lxs[64 * 128];
    __shared__ __align__(16) unsigned char lws[128 * 128];
    const int bid = blockIdx.x;
    const int s = bid >> 3, n0 = (bid & 7) << 7;
    const int tid = threadIdx.x, lane = tid & 63, wid = tid >> 6;
    const int idx = lidx[s];
    const float* wb = w + (size_t)idx * O_ * D_ + (size_t)n0 * D_;
    const float* xb = x + (size_t)s * D_;
    const int swz = (lane & 7) << 4;
    const int kb = (lane >> 4) << 4;
    const int a_base = (lane & 15) * 128 + kb;
    const int b_base = (wid * 32 + (lane & 15)) * 128 + kb;
    f32x4 acc[4][2];
    #pragma unroll
    for (int i = 0; i < 4; ++i)
        #pragma unroll
        for (int j = 0; j < 2; ++j) acc[i][j] = (f32x4)0.0f;
    for (int kt = 0; kt < D_; kt += 64) {
        __syncthreads();
        #pragma unroll
        for (int p = 0; p < 4; ++p) {
            int f = tid + p * 256, row = f >> 4, c = (f & 15) << 2;
            const float4 v = *reinterpret_cast<const float4*>(
                xb + (size_t)row * (S_ * D_) + kt + c);
            uint2 pk = { f2bf2(v.x, v.y), f2bf2(v.z, v.w) };
            *reinterpret_cast<uint2*>(&lxs[(row * 128 + c * 2) ^ ((row & 7) << 4)]) = pk;
        }
        #pragma unroll
        for (int p = 0; p < 8; ++p) {
            int f = tid + p * 256, row = f >> 4, c = (f & 15) << 2;
            const float4 v = *reinterpret_cast<const float4*>(
                wb + (size_t)row * D_ + kt + c);
            uint2 pk = { f2bf2(v.x, v.y), f2bf2(v.z, v.w) };
            *reinterpret_cast<uint2*>(&lws[(row * 128 + c * 2) ^ ((row & 7) << 4)]) = pk;
        }
        __syncthreads();
        #pragma unroll
        for (int kk = 0; kk < 2; ++kk) {
            bf16x8 af[4], bfr[2];
            #pragma unroll
            for (int mi = 0; mi < 4; ++mi)
                af[mi] = *reinterpret_cast<const bf16x8*>(
                    &lxs[(((a_base + kk * 64) ^ swz) + mi * 2048)]);
            #pragma unroll
            for (int ni = 0; ni < 2; ++ni)
                bfr[ni] = *reinterpret_cast<const bf16x8*>(
                    &lws[(((b_base + kk * 64) ^ swz) + ni * 2048)]);
            #pragma unroll
            for (int mi = 0; mi < 4; ++mi)
                #pragma unroll
                for (int ni = 0; ni < 2; ++ni)
                    acc[mi][ni] = __builtin_amdgcn_mfma_f32_16x16x32_bf16(
                        af[mi], bfr[ni], acc[mi][ni], 0, 0, 0);
        }
    }
    float* ob = out + (size_t)s * O_ + n0 + wid * 32 + (lane & 15);
    const int r0 = (lane >> 4) << 2;
    #pragma unroll
    for (int mi = 0; mi < 4; ++mi)
        #pragma unroll
        for (int ni = 0; ni < 2; ++ni)
            #pragma unroll
            for (int r = 0; r < 4; ++r) {
                int b = mi * 16 + r0 + r;
                ob[(size_t)b * (S_ * O_) + ni * 16] = acc[mi][ni][r];
            }
}

extern "C" void kernel_launch(void* const* d_in, const int* in_sizes, int n_in,
                              void* d_out, int out_size, void* d_ws, size_t ws_size,
                              hipStream_t stream) {
    const float* x  = (const float*)d_in[0];
    const int* lidx = (const int*)d_in[1];
    const float* w  = (const float*)d_in[2];
    float* out      = (float*)d_out;

    if (ws_size < WS_NEED) {
        moshi_flin_fallback<<<dim3(128 * 8), dim3(256), 0, stream>>>(x, lidx, w, out);
        return;
    }
    unsigned char* ws = (unsigned char*)d_ws;
    moshi_convert<<<dim3(4096), dim3(256), 0, stream>>>(x, w, lidx, ws);
    // grid: 72 pair slots x 8 n-tiles (blocks beyond npairs exit early)
    moshi_gemm_paired<<<dim3(72 * 8), dim3(256), 0, stream>>>(ws, out);
}